// Round 1
// baseline (401.396 us; speedup 1.0000x reference)
//
#include <hip/hip_runtime.h>
#include <math.h>

#define BB 32
#define TT 256
#define DD 1024
#define NPER 64
#define NNODES 2048
#define EE 65536
#define LN_EPS 1e-5f

__device__ __forceinline__ float gelu_exact(float v) {
    return 0.5f * v * (1.0f + erff(v * 0.70710678118654752f));
}

__global__ void zero_out_kernel(float* __restrict__ out, int n) {
    int i = blockIdx.x * blockDim.x + threadIdx.x;
    if (i < n) out[i] = 0.0f;
}

// LayerNorm of x[:,0,:] -> hnorm (32 x 1024). grid=32, block=256.
__global__ void ln_kernel(const float* __restrict__ x, const float* __restrict__ g,
                          const float* __restrict__ bta, float* __restrict__ hnorm) {
    __shared__ float red[256];
    int b = blockIdx.x;
    int t = threadIdx.x;
    const float* row = x + (size_t)b * TT * DD;  // t index 0
    float v[4];
    float s = 0.0f;
    #pragma unroll
    for (int j = 0; j < 4; ++j) { v[j] = row[t + j * 256]; s += v[j]; }
    red[t] = s; __syncthreads();
    for (int off = 128; off > 0; off >>= 1) {
        if (t < off) red[t] += red[t + off];
        __syncthreads();
    }
    float mu = red[0] * (1.0f / DD);
    __syncthreads();
    float sq = 0.0f;
    #pragma unroll
    for (int j = 0; j < 4; ++j) { float d = v[j] - mu; sq += d * d; }
    red[t] = sq; __syncthreads();
    for (int off = 128; off > 0; off >>= 1) {
        if (t < off) red[t] += red[t + off];
        __syncthreads();
    }
    float rstd = rsqrtf(red[0] * (1.0f / DD) + LN_EPS);
    #pragma unroll
    for (int j = 0; j < 4; ++j) {
        int d = t + j * 256;
        hnorm[b * DD + d] = (v[j] - mu) * rstd * g[d] + bta[d];
    }
}

// energy[b] = gelu(hnorm[b] @ We1 + be1) . We2 + be2. grid=32, block=256.
__global__ __launch_bounds__(256) void energy_kernel(
    const float* __restrict__ hnorm, const float* __restrict__ We1,
    const float* __restrict__ be1, const float* __restrict__ We2,
    const float* __restrict__ be2, float* __restrict__ out) {
    __shared__ float sh[DD];
    __shared__ float red[256];
    int b = blockIdx.x;
    int t = threadIdx.x;
    for (int j = t; j < DD; j += 256) sh[j] = hnorm[b * DD + j];
    __syncthreads();
    float acc[4] = {0.f, 0.f, 0.f, 0.f};
    for (int k = 0; k < DD; ++k) {
        float a = sh[k];
        const float* wrow = We1 + (size_t)k * DD;
        #pragma unroll
        for (int j = 0; j < 4; ++j) acc[j] += a * wrow[t + j * 256];
    }
    float p = 0.0f;
    #pragma unroll
    for (int j = 0; j < 4; ++j) {
        int col = t + j * 256;
        float h = gelu_exact(acc[j] + be1[col]);
        p += h * We2[col];
    }
    red[t] = p; __syncthreads();
    for (int off = 128; off > 0; off >>= 1) {
        if (t < off) red[t] += red[t + off];
        __syncthreads();
    }
    if (t == 0) out[b] = red[0] + be2[0];
}

// P[half][i][n] = sum_k nodes[i][k] * Wf1[half*1024 + k][n]
// nodes[i] = x[i/64][1 + i%64][:]. Tile 64x64, block 256 (16x16 threads, 4x4 microtile).
// grid = (16 ncol-tiles, 32 mrow-tiles, 2 halves)
__global__ __launch_bounds__(256) void pgemm_kernel(
    const float* __restrict__ x, const float* __restrict__ Wf1, float* __restrict__ P) {
    __shared__ float As[64][68];  // As[k][m] (transposed A tile)
    __shared__ float Bs[64][68];  // Bs[k][n]
    int t = threadIdx.x;
    int tx = t & 15;
    int ty = t >> 4;
    int half = blockIdx.z;
    int m0 = blockIdx.y * 64;
    int n0 = blockIdx.x * 64;
    const float* Bbase = Wf1 + (size_t)half * DD * DD;
    float acc[4][4] = {};
    int lsub = t >> 4;       // 0..15 row within group of 16
    int lk4 = (t & 15) * 4;  // float4 column offset

    for (int k0 = 0; k0 < DD; k0 += 64) {
        #pragma unroll
        for (int it = 0; it < 4; ++it) {
            int m = it * 16 + lsub;
            int gi = m0 + m;
            const float* arow =
                x + ((size_t)(gi >> 6) * TT + 1 + (gi & 63)) * DD + k0 + lk4;
            float4 av = *(const float4*)arow;
            As[lk4 + 0][m] = av.x;
            As[lk4 + 1][m] = av.y;
            As[lk4 + 2][m] = av.z;
            As[lk4 + 3][m] = av.w;
            int kb = it * 16 + lsub;
            const float* brow = Bbase + (size_t)(k0 + kb) * DD + n0 + lk4;
            *(float4*)&Bs[kb][lk4] = *(const float4*)brow;
        }
        __syncthreads();
        #pragma unroll 8
        for (int kk = 0; kk < 64; ++kk) {
            float4 a4 = *(const float4*)&As[kk][ty * 4];
            float4 b4 = *(const float4*)&Bs[kk][tx * 4];
            float a[4] = {a4.x, a4.y, a4.z, a4.w};
            float bb[4] = {b4.x, b4.y, b4.z, b4.w};
            #pragma unroll
            for (int i = 0; i < 4; ++i)
                #pragma unroll
                for (int j = 0; j < 4; ++j) acc[i][j] += a[i] * bb[j];
        }
        __syncthreads();
    }
    float* Pout = P + (size_t)half * NNODES * DD;
    #pragma unroll
    for (int i = 0; i < 4; ++i) {
        int m = m0 + ty * 4 + i;
        float4 o = make_float4(acc[i][0], acc[i][1], acc[i][2], acc[i][3]);
        *(float4*)&Pout[(size_t)m * DD + n0 + tx * 4] = o;
    }
}

// One wave per edge: fm = gelu(P0[ei0]+P1[ei1]+bf1) . Wf2 + bf2;
// forces[ei0] += fm * vec / dist. grid = E/4, block = 256 (4 waves).
__global__ __launch_bounds__(256) void edge_kernel(
    const float* __restrict__ P, const int* __restrict__ edge_index,
    const float* __restrict__ evec, const float* __restrict__ edist,
    const float* __restrict__ bf1, const float* __restrict__ Wf2,
    const float* __restrict__ bf2, float* __restrict__ forces) {
    int wave = threadIdx.x >> 6;
    int lane = threadIdx.x & 63;
    int e = blockIdx.x * 4 + wave;
    int i0 = edge_index[e];
    int i1 = edge_index[EE + e];
    const float* p0 = P + (size_t)i0 * DD;
    const float* p1 = P + (size_t)NNODES * DD + (size_t)i1 * DD;
    float acc = 0.0f;
    #pragma unroll
    for (int j = 0; j < 16; ++j) {
        int d = j * 64 + lane;
        float hv = p0[d] + p1[d] + bf1[d];
        acc += gelu_exact(hv) * Wf2[d];
    }
    #pragma unroll
    for (int off = 32; off > 0; off >>= 1) acc += __shfl_xor(acc, off, 64);
    float fm = acc + bf2[0];
    if (lane < 3) {
        float s = fm / edist[e];
        atomicAdd(&forces[i0 * 3 + lane], s * evec[e * 3 + lane]);
    }
}

extern "C" void kernel_launch(void* const* d_in, const int* in_sizes, int n_in,
                              void* d_out, int out_size, void* d_ws, size_t ws_size,
                              hipStream_t stream) {
    const float* x    = (const float*)d_in[0];
    // d_in[1] = batch (unused: segment ids come from edge_index[0])
    const int* edge_index = (const int*)d_in[2];
    const float* evec = (const float*)d_in[3];
    const float* edist = (const float*)d_in[4];
    // d_in[5] = natoms (compile-time constant 64)
    const float* ln_g = (const float*)d_in[6];
    const float* ln_b = (const float*)d_in[7];
    const float* We1  = (const float*)d_in[8];
    const float* be1  = (const float*)d_in[9];
    const float* We2  = (const float*)d_in[10];
    const float* be2  = (const float*)d_in[11];
    const float* Wf1  = (const float*)d_in[12];
    const float* bf1  = (const float*)d_in[13];
    const float* Wf2  = (const float*)d_in[14];
    const float* bf2  = (const float*)d_in[15];

    float* out = (float*)d_out;  // [0:32] energy, [32:32+6144] forces
    float* hnorm = (float*)d_ws;            // 32*1024 floats = 128 KB
    float* P = hnorm + BB * DD;             // 2*2048*1024 floats = 16 MB

    int total_out = BB + NNODES * 3;
    zero_out_kernel<<<(total_out + 255) / 256, 256, 0, stream>>>(out, total_out);
    ln_kernel<<<BB, 256, 0, stream>>>(x, ln_g, ln_b, hnorm);
    energy_kernel<<<BB, 256, 0, stream>>>(hnorm, We1, be1, We2, be2, out);
    pgemm_kernel<<<dim3(16, 32, 2), 256, 0, stream>>>(x, Wf1, P);
    edge_kernel<<<EE / 4, 256, 0, stream>>>(P, edge_index, evec, edist, bf1, Wf2,
                                            bf2, out + BB);
}

// Round 2
// 304.061 us; speedup vs baseline: 1.3201x; 1.3201x over previous
//
#include <hip/hip_runtime.h>
#include <math.h>

#define BB 32
#define TT 256
#define DD 1024
#define NNODES 2048
#define EE 65536
#define LN_EPS 1e-5f

typedef __attribute__((ext_vector_type(8))) short shortx8;
typedef __attribute__((ext_vector_type(4))) float floatx4;
typedef __attribute__((ext_vector_type(8))) unsigned short ushortx8;

__device__ __forceinline__ float gelu_exact(float v) {
    return 0.5f * v * (1.0f + erff(v * 0.70710678118654752f));
}

__device__ __forceinline__ unsigned short f32_to_bf16(float f) {
    unsigned u = __float_as_uint(f);
    unsigned r = (u + 0x7FFF + ((u >> 16) & 1)) >> 16;
    return (unsigned short)r;
}

__device__ __forceinline__ float bf16_to_f32(unsigned short h) {
    return __uint_as_float(((unsigned)h) << 16);
}

__device__ __forceinline__ void load_lds16(const void* g, void* l) {
    __builtin_amdgcn_global_load_lds(
        (const __attribute__((address_space(1))) void*)g,
        (__attribute__((address_space(3))) void*)l, 16, 0, 0);
}

__global__ void zero_out_kernel(float* __restrict__ out, int n) {
    int i = blockIdx.x * blockDim.x + threadIdx.x;
    if (i < n) out[i] = 0.0f;
}

// LayerNorm of x[:,0,:] -> hnorm (32 x 1024). grid=32, block=256.
__global__ void ln_kernel(const float* __restrict__ x, const float* __restrict__ g,
                          const float* __restrict__ bta, float* __restrict__ hnorm) {
    __shared__ float red[256];
    int b = blockIdx.x;
    int t = threadIdx.x;
    const float* row = x + (size_t)b * TT * DD;
    float v[4];
    float s = 0.0f;
    #pragma unroll
    for (int j = 0; j < 4; ++j) { v[j] = row[t + j * 256]; s += v[j]; }
    red[t] = s; __syncthreads();
    for (int off = 128; off > 0; off >>= 1) {
        if (t < off) red[t] += red[t + off];
        __syncthreads();
    }
    float mu = red[0] * (1.0f / DD);
    __syncthreads();
    float sq = 0.0f;
    #pragma unroll
    for (int j = 0; j < 4; ++j) { float d = v[j] - mu; sq += d * d; }
    red[t] = sq; __syncthreads();
    for (int off = 128; off > 0; off >>= 1) {
        if (t < off) red[t] += red[t + off];
        __syncthreads();
    }
    float rstd = rsqrtf(red[0] * (1.0f / DD) + LN_EPS);
    #pragma unroll
    for (int j = 0; j < 4; ++j) {
        int d = t + j * 256;
        hnorm[b * DD + d] = (v[j] - mu) * rstd * g[d] + bta[d];
    }
}

// Split-K partial GEMM: He[ks][32][col] = sum_{k in chunk ks} h[r][k]*We1[k][col]
// grid (4 col-tiles of 256, 8 k-splits of 128), block 256.
__global__ __launch_bounds__(256) void energy1_kernel(
    const float* __restrict__ hnorm, const float* __restrict__ We1,
    float* __restrict__ He) {
    int col = blockIdx.x * 256 + threadIdx.x;
    int k0 = blockIdx.y * 128;
    float acc[32];
    #pragma unroll
    for (int r = 0; r < 32; ++r) acc[r] = 0.0f;
    for (int k = 0; k < 128; ++k) {
        float w = We1[(size_t)(k0 + k) * DD + col];
        #pragma unroll
        for (int r = 0; r < 32; ++r) acc[r] += hnorm[r * DD + k0 + k] * w;
    }
    float* o = He + (size_t)blockIdx.y * 32 * DD;
    #pragma unroll
    for (int r = 0; r < 32; ++r) o[r * DD + col] = acc[r];
}

// Epilogue: sum partials, gelu, dot We2. grid=32, block=256.
__global__ __launch_bounds__(256) void energy2_kernel(
    const float* __restrict__ He, const float* __restrict__ be1,
    const float* __restrict__ We2, const float* __restrict__ be2,
    float* __restrict__ out) {
    __shared__ float red[256];
    int b = blockIdx.x;
    int t = threadIdx.x;
    float p = 0.0f;
    #pragma unroll
    for (int j = 0; j < 4; ++j) {
        int c = t * 4 + j;
        float s = 0.0f;
        #pragma unroll
        for (int ks = 0; ks < 8; ++ks) s += He[(size_t)ks * 32 * DD + b * DD + c];
        s += be1[c];
        p += gelu_exact(s) * We2[c];
    }
    red[t] = p; __syncthreads();
    for (int off = 128; off > 0; off >>= 1) {
        if (t < off) red[t] += red[t + off];
        __syncthreads();
    }
    if (t == 0) out[b] = red[0] + be2[0];
}

// x node slices -> bf16 nodesB[2048][1024]. grid 2048, block 256 (4 els/thread).
__global__ void prep_nodes_kernel(const float* __restrict__ x,
                                  unsigned short* __restrict__ nodesB) {
    int idx4 = (blockIdx.x * 256 + threadIdx.x) * 4;
    int i = idx4 >> 10;
    int k = idx4 & 1023;
    const float* src = x + ((size_t)(i >> 6) * TT + 1 + (i & 63)) * DD + k;
    float4 v = *(const float4*)src;
    ushort4 o;
    o.x = f32_to_bf16(v.x); o.y = f32_to_bf16(v.y);
    o.z = f32_to_bf16(v.z); o.w = f32_to_bf16(v.w);
    *(ushort4*)&nodesB[idx4] = o;
}

// Wf1[2048][1024] fp32 -> Wf1T[half][n][k] bf16 (k within half, 1024).
// grid (32 n-tiles, 64 k-tiles), block 256 = (tx 32, ty 8). 32x32 tiles.
__global__ __launch_bounds__(256) void prep_wf1t_kernel(
    const float* __restrict__ Wf1, unsigned short* __restrict__ Wf1T) {
    __shared__ float tile[32][33];
    int tx = threadIdx.x & 31;
    int ty = threadIdx.x >> 5;
    int n0 = blockIdx.x * 32;
    int kg0 = blockIdx.y * 32;  // global k 0..2047
    #pragma unroll
    for (int j = 0; j < 4; ++j) {
        int r = ty * 4 + j;  // k-row in tile
        tile[r][tx] = Wf1[(size_t)(kg0 + r) * DD + n0 + tx];
    }
    __syncthreads();
    int half = kg0 >> 10;
    int kk0 = kg0 & 1023;
    unsigned short* o = Wf1T + (size_t)half * DD * DD;
    #pragma unroll
    for (int j = 0; j < 4; ++j) {
        int rn = ty * 4 + j;  // n-row of output
        o[(size_t)(n0 + rn) * DD + kk0 + tx] = f32_to_bf16(tile[tx][rn]);
    }
}

// MFMA GEMM: P[half][i][n] = sum_k nodesB[i][k] * Wf1T[half][n][k]  (bf16 in/out)
// A-operand = Wf1T rows (m-dim = n), B-operand = nodesB rows (n-dim = i).
// Tile 128(n) x 128(i), BK=64. grid (8 n-tiles, 16 i-tiles, 2 halves), block 256.
__global__ __launch_bounds__(256) void pgemm_mfma_kernel(
    const unsigned short* __restrict__ nodesB,
    const unsigned short* __restrict__ Wf1T, unsigned short* __restrict__ P) {
    __shared__ unsigned short As[128 * 64];  // [n-row][k] 16 KB, XOR-swizzled chunks
    __shared__ unsigned short Bs[128 * 64];  // [i-row][k]
    int t = threadIdx.x;
    int w = t >> 6;
    int lane = t & 63;
    int quad = lane >> 4;
    int l16 = lane & 15;
    int wn = (w & 1) * 64;
    int wi = (w >> 1) * 64;
    int half = blockIdx.z;
    int n0 = blockIdx.x * 128;
    int i0 = blockIdx.y * 128;

    const unsigned short* Ag = Wf1T + (size_t)half * DD * DD;
    const unsigned short* Bg = nodesB;

    // staging source offsets: lane -> (row within 8-row group, swizzled chunk)
    int sr = lane >> 3;
    int sc = (lane & 7) ^ sr;
    size_t aoff[4], boff[4];
    #pragma unroll
    for (int j = 0; j < 4; ++j) {
        aoff[j] = (size_t)(n0 + w * 32 + j * 8 + sr) * DD + sc * 8;
        boff[j] = (size_t)(i0 + w * 32 + j * 8 + sr) * DD + sc * 8;
    }

    floatx4 acc[4][4];
    #pragma unroll
    for (int a = 0; a < 4; ++a)
        #pragma unroll
        for (int b = 0; b < 4; ++b) {
            acc[a][b][0] = 0.f; acc[a][b][1] = 0.f;
            acc[a][b][2] = 0.f; acc[a][b][3] = 0.f;
        }

    for (int k0 = 0; k0 < DD; k0 += 64) {
        #pragma unroll
        for (int j = 0; j < 4; ++j) {
            load_lds16(Ag + aoff[j] + k0, (void*)(As + (w * 32 + j * 8) * 64));
            load_lds16(Bg + boff[j] + k0, (void*)(Bs + (w * 32 + j * 8) * 64));
        }
        __syncthreads();
        #pragma unroll
        for (int s = 0; s < 2; ++s) {
            shortx8 af[4], bfr[4];
            #pragma unroll
            for (int f = 0; f < 4; ++f) {
                int rn = wn + f * 16 + l16;
                af[f] = *(const shortx8*)&As[rn * 64 + ((((s << 2) | quad) ^ (rn & 7)) << 3)];
                int ri = wi + f * 16 + l16;
                bfr[f] = *(const shortx8*)&Bs[ri * 64 + ((((s << 2) | quad) ^ (ri & 7)) << 3)];
            }
            #pragma unroll
            for (int fa = 0; fa < 4; ++fa)
                #pragma unroll
                for (int fb = 0; fb < 4; ++fb)
                    acc[fa][fb] = __builtin_amdgcn_mfma_f32_16x16x32_bf16(
                        af[fa], bfr[fb], acc[fa][fb], 0, 0, 0);
        }
        __syncthreads();
    }

    // D row (quad*4+reg) = n-dim, col (l16) = i-dim -> 4 consecutive n per lane
    unsigned short* Pout = P + (size_t)half * NNODES * DD;
    #pragma unroll
    for (int fa = 0; fa < 4; ++fa) {
        #pragma unroll
        for (int fb = 0; fb < 4; ++fb) {
            int n = n0 + wn + fa * 16 + quad * 4;
            int i = i0 + wi + fb * 16 + l16;
            floatx4 v = acc[fa][fb];
            ushort4 o;
            o.x = f32_to_bf16(v[0]); o.y = f32_to_bf16(v[1]);
            o.z = f32_to_bf16(v[2]); o.w = f32_to_bf16(v[3]);
            *(ushort4*)&Pout[(size_t)i * DD + n] = o;
        }
    }
}

// One wave per edge: fm = gelu(P0[ei0]+P1[ei1]+bf1) . Wf2 + bf2 (P in bf16);
// forces[ei0] += fm * vec / dist. grid = E/4, block = 256 (4 waves).
__global__ __launch_bounds__(256) void edge_kernel(
    const unsigned short* __restrict__ P, const int* __restrict__ edge_index,
    const float* __restrict__ evec, const float* __restrict__ edist,
    const float* __restrict__ bf1, const float* __restrict__ Wf2,
    const float* __restrict__ bf2, float* __restrict__ forces) {
    int wave = threadIdx.x >> 6;
    int lane = threadIdx.x & 63;
    int e = blockIdx.x * 4 + wave;
    int i0 = edge_index[e];
    int i1 = edge_index[EE + e];
    const unsigned short* p0 = P + (size_t)i0 * DD;
    const unsigned short* p1 = P + (size_t)NNODES * DD + (size_t)i1 * DD;
    float acc = 0.0f;
    #pragma unroll
    for (int s = 0; s < 2; ++s) {
        int d0 = s * 512 + lane * 8;
        ushortx8 u0 = *(const ushortx8*)(p0 + d0);
        ushortx8 u1 = *(const ushortx8*)(p1 + d0);
        float4 b0 = *(const float4*)(bf1 + d0);
        float4 b1 = *(const float4*)(bf1 + d0 + 4);
        float4 w0 = *(const float4*)(Wf2 + d0);
        float4 w1 = *(const float4*)(Wf2 + d0 + 4);
        float bb[8] = {b0.x, b0.y, b0.z, b0.w, b1.x, b1.y, b1.z, b1.w};
        float ww[8] = {w0.x, w0.y, w0.z, w0.w, w1.x, w1.y, w1.z, w1.w};
        #pragma unroll
        for (int j = 0; j < 8; ++j) {
            float hv = bf16_to_f32(u0[j]) + bf16_to_f32(u1[j]) + bb[j];
            acc += gelu_exact(hv) * ww[j];
        }
    }
    #pragma unroll
    for (int off = 32; off > 0; off >>= 1) acc += __shfl_xor(acc, off, 64);
    float fm = acc + bf2[0];
    if (lane < 3) {
        float s = fm / edist[e];
        atomicAdd(&forces[i0 * 3 + lane], s * evec[e * 3 + lane]);
    }
}

extern "C" void kernel_launch(void* const* d_in, const int* in_sizes, int n_in,
                              void* d_out, int out_size, void* d_ws, size_t ws_size,
                              hipStream_t stream) {
    const float* x    = (const float*)d_in[0];
    const int* edge_index = (const int*)d_in[2];
    const float* evec = (const float*)d_in[3];
    const float* edist = (const float*)d_in[4];
    const float* ln_g = (const float*)d_in[6];
    const float* ln_b = (const float*)d_in[7];
    const float* We1  = (const float*)d_in[8];
    const float* be1  = (const float*)d_in[9];
    const float* We2  = (const float*)d_in[10];
    const float* be2  = (const float*)d_in[11];
    const float* Wf1  = (const float*)d_in[12];
    const float* bf1  = (const float*)d_in[13];
    const float* Wf2  = (const float*)d_in[14];
    const float* bf2  = (const float*)d_in[15];

    float* out = (float*)d_out;  // [0:32] energy, [32:32+6144] forces

    // ws layout (16 MB total):
    // [0, 8MB)    : P bf16 [2][2048][1024] -- during energy phase the first
    //               1.125 MB doubles as hnorm (128 KB) + He (1 MB); P is
    //               written only after energy2 consumed them.
    // [8MB, 12MB) : nodesB bf16 [2048][1024]
    // [12MB,16MB) : Wf1T  bf16 [2][1024][1024]
    char* wsb = (char*)d_ws;
    unsigned short* P      = (unsigned short*)(wsb);
    float* hnorm           = (float*)(wsb);
    float* He              = (float*)(wsb + (128 << 10));
    unsigned short* nodesB = (unsigned short*)(wsb + (8u << 20));
    unsigned short* Wf1T   = (unsigned short*)(wsb + (12u << 20));

    int total_out = BB + NNODES * 3;
    zero_out_kernel<<<(total_out + 255) / 256, 256, 0, stream>>>(out, total_out);
    ln_kernel<<<BB, 256, 0, stream>>>(x, ln_g, ln_b, hnorm);
    energy1_kernel<<<dim3(4, 8), 256, 0, stream>>>(hnorm, We1, He);
    energy2_kernel<<<BB, 256, 0, stream>>>(He, be1, We2, be2, out);
    prep_nodes_kernel<<<NNODES * DD / 1024, 256, 0, stream>>>(x, nodesB);
    prep_wf1t_kernel<<<dim3(32, 64), 256, 0, stream>>>(Wf1, Wf1T);
    pgemm_mfma_kernel<<<dim3(8, 16, 2), 256, 0, stream>>>(nodesB, Wf1T, P);
    edge_kernel<<<EE / 4, 256, 0, stream>>>(P, edge_index, evec, edist, bf1, Wf2,
                                            bf2, out + BB);
}

// Round 3
// 191.722 us; speedup vs baseline: 2.0936x; 1.5859x over previous
//
#include <hip/hip_runtime.h>
#include <math.h>

#define BB 32
#define TT 256
#define DD 1024
#define NNODES 2048
#define EE 65536
#define LN_EPS 1e-5f

typedef __attribute__((ext_vector_type(8))) short shortx8;
typedef __attribute__((ext_vector_type(4))) float floatx4;
typedef __attribute__((ext_vector_type(8))) unsigned short ushortx8;

__device__ __forceinline__ float gelu_fast(float x) {
    // tanh-approx gelu: x*(1 - 1/(1+exp2(K*x*(1+0.044715*x^2)))), K=2*sqrt(2/pi)*log2(e)
    float x2 = x * x;
    float z = x * fmaf(0.10294456f, x2, 2.30211786f);
    float e = __builtin_amdgcn_exp2f(z);
    float r = __builtin_amdgcn_rcpf(1.0f + e);
    return fmaf(-x, r, x);
}

__device__ __forceinline__ unsigned short f32_to_bf16(float f) {
    unsigned u = __float_as_uint(f);
    unsigned r = (u + 0x7FFF + ((u >> 16) & 1)) >> 16;
    return (unsigned short)r;
}

__device__ __forceinline__ float bf16_to_f32(unsigned short h) {
    return __uint_as_float(((unsigned)h) << 16);
}

__device__ __forceinline__ void load_lds16(const void* g, void* l) {
    __builtin_amdgcn_global_load_lds(
        (const __attribute__((address_space(1))) void*)g,
        (__attribute__((address_space(3))) void*)l, 16, 0, 0);
}

__global__ void zero_out_kernel(float* __restrict__ out, int n) {
    int i = blockIdx.x * blockDim.x + threadIdx.x;
    if (i < n) out[i] = 0.0f;
}

// LayerNorm of x[:,0,:] -> hnorm (32 x 1024). grid=32, block=256.
__global__ void ln_kernel(const float* __restrict__ x, const float* __restrict__ g,
                          const float* __restrict__ bta, float* __restrict__ hnorm) {
    __shared__ float red[256];
    int b = blockIdx.x;
    int t = threadIdx.x;
    const float* row = x + (size_t)b * TT * DD;
    float v[4];
    float s = 0.0f;
    #pragma unroll
    for (int j = 0; j < 4; ++j) { v[j] = row[t + j * 256]; s += v[j]; }
    red[t] = s; __syncthreads();
    for (int off = 128; off > 0; off >>= 1) {
        if (t < off) red[t] += red[t + off];
        __syncthreads();
    }
    float mu = red[0] * (1.0f / DD);
    __syncthreads();
    float sq = 0.0f;
    #pragma unroll
    for (int j = 0; j < 4; ++j) { float d = v[j] - mu; sq += d * d; }
    red[t] = sq; __syncthreads();
    for (int off = 128; off > 0; off >>= 1) {
        if (t < off) red[t] += red[t + off];
        __syncthreads();
    }
    float rstd = rsqrtf(red[0] * (1.0f / DD) + LN_EPS);
    #pragma unroll
    for (int j = 0; j < 4; ++j) {
        int d = t + j * 256;
        hnorm[b * DD + d] = (v[j] - mu) * rstd * g[d] + bta[d];
    }
}

// Split-K/row partial GEMM: He[ks][r0+r][col] = sum_{k chunk} h[r][k]*We1[k][col]
// grid (4 col-tiles of 256, 8 k-splits of 128, 2 row-groups of 16), block 256.
// acc[16] stays in VGPRs (the R2 version's acc[32] spilled to scratch: VGPR=20).
__global__ __launch_bounds__(256) void energy1_kernel(
    const float* __restrict__ hnorm, const float* __restrict__ We1,
    float* __restrict__ He) {
    __shared__ float hs[128 * 16];  // [k][r], broadcast reads
    int t = threadIdx.x;
    int col = blockIdx.x * 256 + t;
    int k0 = blockIdx.y * 128;
    int r0 = blockIdx.z * 16;
    for (int idx = t; idx < 128 * 16; idx += 256) {
        int r = idx & 15, k = idx >> 4;
        hs[idx] = hnorm[(size_t)(r0 + r) * DD + k0 + k];
    }
    __syncthreads();
    float acc[16];
    #pragma unroll
    for (int r = 0; r < 16; ++r) acc[r] = 0.0f;
    #pragma unroll 4
    for (int k = 0; k < 128; ++k) {
        float w = We1[(size_t)(k0 + k) * DD + col];
        const float* hrow = hs + k * 16;
        #pragma unroll
        for (int j = 0; j < 4; ++j) {
            float4 h4 = *(const float4*)(hrow + j * 4);
            acc[j * 4 + 0] = fmaf(h4.x, w, acc[j * 4 + 0]);
            acc[j * 4 + 1] = fmaf(h4.y, w, acc[j * 4 + 1]);
            acc[j * 4 + 2] = fmaf(h4.z, w, acc[j * 4 + 2]);
            acc[j * 4 + 3] = fmaf(h4.w, w, acc[j * 4 + 3]);
        }
    }
    float* o = He + (size_t)blockIdx.y * 32 * DD;
    #pragma unroll
    for (int r = 0; r < 16; ++r) o[(size_t)(r0 + r) * DD + col] = acc[r];
}

// Epilogue: sum partials, gelu, dot We2. grid=32, block=256.
__global__ __launch_bounds__(256) void energy2_kernel(
    const float* __restrict__ He, const float* __restrict__ be1,
    const float* __restrict__ We2, const float* __restrict__ be2,
    float* __restrict__ out) {
    __shared__ float red[256];
    int b = blockIdx.x;
    int t = threadIdx.x;
    float p = 0.0f;
    #pragma unroll
    for (int j = 0; j < 4; ++j) {
        int c = t * 4 + j;
        float s = 0.0f;
        #pragma unroll
        for (int ks = 0; ks < 8; ++ks) s += He[(size_t)ks * 32 * DD + b * DD + c];
        s += be1[c];
        p += gelu_fast(s) * We2[c];
    }
    red[t] = p; __syncthreads();
    for (int off = 128; off > 0; off >>= 1) {
        if (t < off) red[t] += red[t + off];
        __syncthreads();
    }
    if (t == 0) out[b] = red[0] + be2[0];
}

// x node slices -> bf16 nodesB[2048][1024]. grid 2048, block 256 (4 els/thread).
__global__ void prep_nodes_kernel(const float* __restrict__ x,
                                  unsigned short* __restrict__ nodesB) {
    int idx4 = (blockIdx.x * 256 + threadIdx.x) * 4;
    int i = idx4 >> 10;
    int k = idx4 & 1023;
    const float* src = x + ((size_t)(i >> 6) * TT + 1 + (i & 63)) * DD + k;
    float4 v = *(const float4*)src;
    ushort4 o;
    o.x = f32_to_bf16(v.x); o.y = f32_to_bf16(v.y);
    o.z = f32_to_bf16(v.z); o.w = f32_to_bf16(v.w);
    *(ushort4*)&nodesB[idx4] = o;
}

// Wf1[2048][1024] fp32 -> Wf1T[half][n][k] bf16 (k within half, 1024).
// grid (32 n-tiles, 64 k-tiles), block 256 = (tx 32, ty 8). 32x32 tiles.
__global__ __launch_bounds__(256) void prep_wf1t_kernel(
    const float* __restrict__ Wf1, unsigned short* __restrict__ Wf1T) {
    __shared__ float tile[32][33];
    int tx = threadIdx.x & 31;
    int ty = threadIdx.x >> 5;
    int n0 = blockIdx.x * 32;
    int kg0 = blockIdx.y * 32;  // global k 0..2047
    #pragma unroll
    for (int j = 0; j < 4; ++j) {
        int r = ty * 4 + j;  // k-row in tile
        tile[r][tx] = Wf1[(size_t)(kg0 + r) * DD + n0 + tx];
    }
    __syncthreads();
    int half = kg0 >> 10;
    int kk0 = kg0 & 1023;
    unsigned short* o = Wf1T + (size_t)half * DD * DD;
    #pragma unroll
    for (int j = 0; j < 4; ++j) {
        int rn = ty * 4 + j;  // n-row of output
        o[(size_t)(n0 + rn) * DD + kk0 + tx] = f32_to_bf16(tile[tx][rn]);
    }
}

// MFMA GEMM: P[half][i][n] = sum_k nodesB[i][k] * Wf1T[half][n][k]  (bf16 in/out)
// bf1 is folded into half 0 of P so the edge kernel skips it entirely.
// Tile 128(n) x 128(i), BK=64. grid (8 n-tiles, 16 i-tiles, 2 halves), block 256.
__global__ __launch_bounds__(256) void pgemm_mfma_kernel(
    const unsigned short* __restrict__ nodesB,
    const unsigned short* __restrict__ Wf1T, const float* __restrict__ bf1,
    unsigned short* __restrict__ P) {
    __shared__ unsigned short As[128 * 64];  // [n-row][k], XOR-swizzled chunks
    __shared__ unsigned short Bs[128 * 64];  // [i-row][k]
    int t = threadIdx.x;
    int w = t >> 6;
    int lane = t & 63;
    int quad = lane >> 4;
    int l16 = lane & 15;
    int wn = (w & 1) * 64;
    int wi = (w >> 1) * 64;
    int half = blockIdx.z;
    int n0 = blockIdx.x * 128;
    int i0 = blockIdx.y * 128;

    const unsigned short* Ag = Wf1T + (size_t)half * DD * DD;
    const unsigned short* Bg = nodesB;

    int sr = lane >> 3;
    int sc = (lane & 7) ^ sr;
    size_t aoff[4], boff[4];
    #pragma unroll
    for (int j = 0; j < 4; ++j) {
        aoff[j] = (size_t)(n0 + w * 32 + j * 8 + sr) * DD + sc * 8;
        boff[j] = (size_t)(i0 + w * 32 + j * 8 + sr) * DD + sc * 8;
    }

    floatx4 acc[4][4];
    #pragma unroll
    for (int a = 0; a < 4; ++a)
        #pragma unroll
        for (int b = 0; b < 4; ++b) {
            acc[a][b][0] = 0.f; acc[a][b][1] = 0.f;
            acc[a][b][2] = 0.f; acc[a][b][3] = 0.f;
        }

    for (int k0 = 0; k0 < DD; k0 += 64) {
        #pragma unroll
        for (int j = 0; j < 4; ++j) {
            load_lds16(Ag + aoff[j] + k0, (void*)(As + (w * 32 + j * 8) * 64));
            load_lds16(Bg + boff[j] + k0, (void*)(Bs + (w * 32 + j * 8) * 64));
        }
        __syncthreads();
        #pragma unroll
        for (int s = 0; s < 2; ++s) {
            shortx8 af[4], bfr[4];
            #pragma unroll
            for (int f = 0; f < 4; ++f) {
                int rn = wn + f * 16 + l16;
                af[f] = *(const shortx8*)&As[rn * 64 + ((((s << 2) | quad) ^ (rn & 7)) << 3)];
                int ri = wi + f * 16 + l16;
                bfr[f] = *(const shortx8*)&Bs[ri * 64 + ((((s << 2) | quad) ^ (ri & 7)) << 3)];
            }
            #pragma unroll
            for (int fa = 0; fa < 4; ++fa)
                #pragma unroll
                for (int fb = 0; fb < 4; ++fb)
                    acc[fa][fb] = __builtin_amdgcn_mfma_f32_16x16x32_bf16(
                        af[fa], bfr[fb], acc[fa][fb], 0, 0, 0);
        }
        __syncthreads();
    }

    // D row (quad*4+reg) = n-dim, col (l16) = i-dim -> 4 consecutive n per lane
    unsigned short* Pout = P + (size_t)half * NNODES * DD;
    #pragma unroll
    for (int fa = 0; fa < 4; ++fa) {
        int n = n0 + wn + fa * 16 + quad * 4;
        float4 badd = make_float4(0.f, 0.f, 0.f, 0.f);
        if (half == 0) badd = *(const float4*)(bf1 + n);
        #pragma unroll
        for (int fb = 0; fb < 4; ++fb) {
            int i = i0 + wi + fb * 16 + l16;
            floatx4 v = acc[fa][fb];
            ushort4 o;
            o.x = f32_to_bf16(v[0] + badd.x);
            o.y = f32_to_bf16(v[1] + badd.y);
            o.z = f32_to_bf16(v[2] + badd.z);
            o.w = f32_to_bf16(v[3] + badd.w);
            *(ushort4*)&Pout[(size_t)i * DD + n] = o;
        }
    }
}

// Wave per 8 edges: fm = gelu(P0'[ei0]+P1[ei1]).Wf2 + bf2 (bf1 pre-folded in P0').
// Wf2 preloaded to 16 VGPRs once per wave. grid = 2048 blocks x 256 (8192 waves).
__global__ __launch_bounds__(256) void edge_kernel(
    const unsigned short* __restrict__ P, const int* __restrict__ edge_index,
    const float* __restrict__ evec, const float* __restrict__ edist,
    const float* __restrict__ Wf2, const float* __restrict__ bf2,
    float* __restrict__ forces) {
    int lane = threadIdx.x & 63;
    int wv = blockIdx.x * 4 + (threadIdx.x >> 6);
    int dbase = lane * 8;
    float wreg[16];
    #pragma unroll
    for (int s = 0; s < 2; ++s) {
        float4 a = *(const float4*)(Wf2 + s * 512 + dbase);
        float4 b = *(const float4*)(Wf2 + s * 512 + dbase + 4);
        wreg[s * 8 + 0] = a.x; wreg[s * 8 + 1] = a.y;
        wreg[s * 8 + 2] = a.z; wreg[s * 8 + 3] = a.w;
        wreg[s * 8 + 4] = b.x; wreg[s * 8 + 5] = b.y;
        wreg[s * 8 + 6] = b.z; wreg[s * 8 + 7] = b.w;
    }
    float bias2 = bf2[0];
    for (int e = wv; e < EE; e += 8192) {
        int i0 = edge_index[e];
        int i1 = edge_index[EE + e];
        const unsigned short* p0 = P + (size_t)i0 * DD;
        const unsigned short* p1 = P + (size_t)NNODES * DD + (size_t)i1 * DD;
        float acc = 0.0f;
        #pragma unroll
        for (int s = 0; s < 2; ++s) {
            ushortx8 u0 = *(const ushortx8*)(p0 + s * 512 + dbase);
            ushortx8 u1 = *(const ushortx8*)(p1 + s * 512 + dbase);
            #pragma unroll
            for (int j = 0; j < 8; ++j) {
                float hv = bf16_to_f32((unsigned short)u0[j]) +
                           bf16_to_f32((unsigned short)u1[j]);
                acc = fmaf(gelu_fast(hv), wreg[s * 8 + j], acc);
            }
        }
        #pragma unroll
        for (int off = 32; off > 0; off >>= 1) acc += __shfl_xor(acc, off, 64);
        float fm = acc + bias2;
        if (lane < 3) {
            float sc = fm / edist[e];
            atomicAdd(&forces[i0 * 3 + lane], sc * evec[e * 3 + lane]);
        }
    }
}

extern "C" void kernel_launch(void* const* d_in, const int* in_sizes, int n_in,
                              void* d_out, int out_size, void* d_ws, size_t ws_size,
                              hipStream_t stream) {
    const float* x    = (const float*)d_in[0];
    const int* edge_index = (const int*)d_in[2];
    const float* evec = (const float*)d_in[3];
    const float* edist = (const float*)d_in[4];
    const float* ln_g = (const float*)d_in[6];
    const float* ln_b = (const float*)d_in[7];
    const float* We1  = (const float*)d_in[8];
    const float* be1  = (const float*)d_in[9];
    const float* We2  = (const float*)d_in[10];
    const float* be2  = (const float*)d_in[11];
    const float* Wf1  = (const float*)d_in[12];
    const float* bf1  = (const float*)d_in[13];
    const float* Wf2  = (const float*)d_in[14];
    const float* bf2  = (const float*)d_in[15];

    float* out = (float*)d_out;  // [0:32] energy, [32:32+6144] forces

    // ws layout (16 MB):
    // [0, 8MB)    : P bf16 [2][2048][1024] -- first 1.125 MB doubles as
    //               hnorm (128 KB) + He (1 MB) during the energy phase.
    // [8MB, 12MB) : nodesB bf16 [2048][1024]
    // [12MB,16MB) : Wf1T  bf16 [2][1024][1024]
    char* wsb = (char*)d_ws;
    unsigned short* P      = (unsigned short*)(wsb);
    float* hnorm           = (float*)(wsb);
    float* He              = (float*)(wsb + (128 << 10));
    unsigned short* nodesB = (unsigned short*)(wsb + (8u << 20));
    unsigned short* Wf1T   = (unsigned short*)(wsb + (12u << 20));

    int total_out = BB + NNODES * 3;
    zero_out_kernel<<<(total_out + 255) / 256, 256, 0, stream>>>(out, total_out);
    ln_kernel<<<BB, 256, 0, stream>>>(x, ln_g, ln_b, hnorm);
    energy1_kernel<<<dim3(4, 8, 2), 256, 0, stream>>>(hnorm, We1, He);
    energy2_kernel<<<BB, 256, 0, stream>>>(He, be1, We2, be2, out);
    prep_nodes_kernel<<<NNODES * DD / 1024, 256, 0, stream>>>(x, nodesB);
    prep_wf1t_kernel<<<dim3(32, 64), 256, 0, stream>>>(Wf1, Wf1T);
    pgemm_mfma_kernel<<<dim3(8, 16, 2), 256, 0, stream>>>(nodesB, Wf1T, bf1, P);
    edge_kernel<<<2048, 256, 0, stream>>>(P, edge_index, evec, edist, Wf2, bf2,
                                          out + BB);
}